// Round 10
// baseline (1171.013 us; speedup 1.0000x reference)
//
#include <hip/hip_runtime.h>
#include <hip/hip_bf16.h>
#include <math.h>

using bf16 = __hip_bfloat16;
using u8 = unsigned char;

typedef __attribute__((ext_vector_type(8))) short short8;   // 8 bf16
typedef __attribute__((ext_vector_type(4))) float f32x4;
typedef __attribute__((ext_vector_type(16))) float f32x16;
typedef __attribute__((ext_vector_type(4))) int int4v;
typedef __attribute__((ext_vector_type(8))) int int32x8;
typedef __attribute__((ext_vector_type(2))) unsigned int uint2v;

static constexpr int Bsz = 512, Nn = 8192, Dd = 4096, Hh = 2048;

enum { EPI_BF16 = 0, EPI_SCALE_F32, EPI_BIAS_BF16, EPI_BIAS_F32,
       EPI_FP8, EPI_ENH_FP8, EPI_GELU_FP8 };

// ---------------------------------------------------------------------------
// fp8 e4m3fn encode (RNE) / decode — bit-exact, proven in r7/r8
// ---------------------------------------------------------------------------
__device__ __forceinline__ u8 f32_to_fp8(float x) {
  const unsigned int u = __float_as_uint(x);
  const unsigned int s = (u >> 24) & 0x80u;
  const float ax = fminf(__uint_as_float(u & 0x7fffffffu), 448.0f);
  const unsigned int au = __float_as_uint(ax);
  unsigned int b;
  if (au >= 0x3c800000u) {
    const unsigned int r = au + 0x7ffffu + ((au >> 20) & 1u);
    b = (((r >> 23) - 120u) << 3) | ((r >> 20) & 7u);
    if (b > 0x7eu) b = 0x7eu;
  } else {
    b = (unsigned int)(int)rintf(ax * 512.0f);
  }
  return (u8)(b | s);
}

__device__ __forceinline__ float fp8_to_f32(u8 b) {
  const int e = (b >> 3) & 15, m = b & 7;
  const float v = e ? __uint_as_float((unsigned)((e + 120) << 23) | ((unsigned)m << 20))
                    : (float)m * 0.001953125f;
  return (b & 0x80) ? -v : v;
}

// ---------------------------------------------------------------------------
__device__ __forceinline__ void gload_lds16(const void* g, void* l) {
  __builtin_amdgcn_global_load_lds(
      (const __attribute__((address_space(1))) void*)g,
      (__attribute__((address_space(3))) void*)l, 16, 0, 0);
}

// stage one K-half region: 128 rows x 64 B (8 KB). LDS dest linear
// [row][slotL] (64-B pitch); global source slot s = slotL ^ ((row>>1)&3).
// 4 waves: wave handles rows wave*32..+32 (two issues of 16 rows).
__device__ __forceinline__ void stage_reg(const void* g, char* region,
                                          long grow0, long pitchB, long kbyte,
                                          int wave, int lane) {
  const int rl = lane >> 2, sl = lane & 3;
  const int s = sl ^ ((rl >> 1) & 3);
  const long r0 = (long)(wave << 5) + rl;
  const char* src0 = (const char*)g + (grow0 + r0) * pitchB + kbyte + (s << 4);
  gload_lds16(src0, region + (wave << 11));
  gload_lds16(src0 + 16 * pitchB, region + (wave << 11) + 1024);
}

#define VMCNT8 asm volatile("s_waitcnt vmcnt(8)" ::: "memory")

// ---------------------------------------------------------------------------
// 128x128 NT GEMM, fp8 e4m3 in, f32 accum, MX-scaled 32x32x64 MFMA (scale=1).
// 4 waves (2x2), per-wave 64x64 out (mr=2, nr=2). LDS 64 KB = ring of
// 4 A-regions + 4 B-regions (8 KB each) -> 2 blocks/CU co-resident (the TLP
// that hides barrier/drain stalls). Depth-3 ring, 1 barrier/step, counted
// vmcnt(8) — ledger identical to r9 (4 loads/step/wave, uniform FIFO):
//   prologue: stage h=0,1,2 (12 loads); vmcnt(8) drains h0; barrier.
//   step h: stage h+3 (clamped -> dead region) ; read h ; MFMA ;
//           vmcnt(8) drains h+1 ; barrier  => h+1 landed for ALL waves.
//   region (h+3)&3 = (h-1)&3 overwrite fenced by step-h entry barrier.
// Fragment math identical to r8/r9 (verified): lane l row (l&31),
// pair (l>>5)^((l>>2)&1), 16B halves at off0 / off0^16.
// M,N multiples of 128; K multiple of 128.
// ---------------------------------------------------------------------------
#define READ_AMX(DST, RG)                                                      \
  _Pragma("unroll") for (int mr = 0; mr < 2; ++mr) {                           \
    const int off0 = ((rowA + mr * 32) << 6) + lSw;                            \
    const int4v lo = *reinterpret_cast<const int4v*>((RG) + off0);             \
    const int4v hi = *reinterpret_cast<const int4v*>((RG) + (off0 ^ 16));      \
    DST[mr] = __builtin_shufflevector(lo, hi, 0, 1, 2, 3, 4, 5, 6, 7);         \
  }

#define READ_BMX(DST, RG)                                                      \
  _Pragma("unroll") for (int nr = 0; nr < 2; ++nr) {                           \
    const int off0 = ((rowB + nr * 32) << 6) + lSw;                            \
    const int4v lo = *reinterpret_cast<const int4v*>((RG) + off0);             \
    const int4v hi = *reinterpret_cast<const int4v*>((RG) + (off0 ^ 16));      \
    DST[nr] = __builtin_shufflevector(lo, hi, 0, 1, 2, 3, 4, 5, 6, 7);         \
  }

#define MFMA_MX(AV, BV)                                                        \
  __builtin_amdgcn_s_setprio(1);                                               \
  _Pragma("unroll") for (int mr = 0; mr < 2; ++mr)                             \
  _Pragma("unroll") for (int nr = 0; nr < 2; ++nr)                             \
    acc[mr][nr] = __builtin_amdgcn_mfma_scale_f32_32x32x64_f8f6f4(             \
        AV[mr], BV[nr], acc[mr][nr], 0, 0, 0, 0x7f7f7f7f, 0, 0x7f7f7f7f);      \
  __builtin_amdgcn_s_setprio(0);

template<int EPI>
__global__ __launch_bounds__(256, 2)
void gemm_mx(const u8* __restrict__ A, const u8* __restrict__ Bt,
             void* __restrict__ Cp, const u8* __restrict__ sel,
             const float* __restrict__ bias, float scale,
             int M, int N, int K)
{
  __shared__ char lds[65536];
  const int tid  = threadIdx.x;
  const int lane = tid & 63;
  const int wave = tid >> 6;
  const int wm = wave >> 1;             // 0..1 : A rows wm*64..+64
  const int wn = wave & 1;              // 0..1 : B cols wn*64..+64

  const int nblk = (M >> 7) * (N >> 7);
  const int q8 = nblk >> 3, r8 = nblk & 7;
  const int xcd = blockIdx.x & 7, pos = blockIdx.x >> 3;
  const int wg = (xcd < r8 ? xcd * (q8 + 1) : r8 * (q8 + 1) + (xcd - r8) * q8) + pos;
  const int ntx = N >> 7;
  const long bcol = (long)(wg % ntx) << 7;
  const long brow = (long)(wg / ntx) << 7;

  const int rowA = wm * 64 + (lane & 31);
  const int rowB = wn * 64 + (lane & 31);
  const int lSw = (((lane >> 5) ^ ((lane >> 2) & 1)) << 5) | (((lane >> 1) & 1) << 4);

  char* const Ar = (char*)lds;            // 4 x 8 KB A-half regions
  char* const Br = (char*)lds + 32768;    // 4 x 8 KB B-half regions

  f32x16 acc[2][2] = {};
  const int HT = K >> 6;                  // 64-elem K-halves

  // prologue: stage h = 0,1,2 (FIFO per h: B then A)
#pragma unroll
  for (int h = 0; h < 3; ++h) {
    stage_reg(Bt, Br + h * 8192, bcol, K, (long)h << 6, wave, lane);
    stage_reg(A,  Ar + h * 8192, brow, K, (long)h << 6, wave, lane);
  }
  VMCNT8;                                 // h0 (B0,A0) landed
  __builtin_amdgcn_s_barrier();

  for (int h = 0; h < HT; ++h) {
    const int hn = (h + 3 < HT) ? (h + 3) : (HT - 1);   // clamp: dead region
    const int rg = (h + 3) & 3;
    stage_reg(Bt, Br + rg * 8192, bcol, K, (long)hn << 6, wave, lane);
    stage_reg(A,  Ar + rg * 8192, brow, K, (long)hn << 6, wave, lane);

    int32x8 aF[2], bF[2];
    READ_AMX(aF, Ar + (h & 3) * 8192);
    READ_BMX(bF, Br + (h & 3) * 8192);
    MFMA_MX(aF, bF);

    VMCNT8;                               // drain h+1 only; h+2,h+3 in flight
    __builtin_amdgcn_s_barrier();
  }

  // epilogue: 32x32 C/D layout: col = lane&31, row = (reg&3)+8*(reg>>2)+4*(lane>>5)
#pragma unroll
  for (int mr = 0; mr < 2; ++mr)
#pragma unroll
  for (int nr = 0; nr < 2; ++nr) {
    const long col = bcol + wn * 64 + nr * 32 + (lane & 31);
#pragma unroll
    for (int reg = 0; reg < 16; ++reg) {
      const long row = brow + wm * 64 + mr * 32 +
                       (reg & 3) + 8 * (reg >> 2) + 4 * (lane >> 5);
      const long idx = row * N + col;
      const float v = acc[mr][nr][reg];
      if constexpr (EPI == EPI_BF16) {
        reinterpret_cast<bf16*>(Cp)[idx] = __float2bfloat16(v);
      } else if constexpr (EPI == EPI_FP8) {
        reinterpret_cast<u8*>(Cp)[idx] = f32_to_fp8(v);
      } else if constexpr (EPI == EPI_ENH_FP8) {
        reinterpret_cast<u8*>(Cp)[idx] = f32_to_fp8(fp8_to_f32(sel[idx]) + 0.1f * v);
      } else if constexpr (EPI == EPI_GELU_FP8) {
        const float tt = v + bias[col];
        reinterpret_cast<u8*>(Cp)[idx] =
            f32_to_fp8(0.5f * tt * (1.0f + erff(tt * 0.7071067811865475f)));
      } else if constexpr (EPI == EPI_BIAS_BF16) {
        reinterpret_cast<bf16*>(Cp)[idx] = __float2bfloat16(v + bias[col]);
      } else {
        reinterpret_cast<float*>(Cp)[idx] = v + bias[col];
      }
    }
  }
}

// ---------------------------------------------------------------------------
// 128x128 NT GEMM bf16 (4 waves) — for M=512 GEMMs (q, scores, final)
// ---------------------------------------------------------------------------
template<int EPI>
__global__ __launch_bounds__(256)
void gemm_nt(const bf16* __restrict__ A, const bf16* __restrict__ Bt,
             void* __restrict__ Cp, const float* __restrict__ bias, float scale,
             int M, int N, int K)
{
  __shared__ bf16 As[128 * 64];
  __shared__ bf16 Bs[128 * 64];
  const int tid  = threadIdx.x;
  const int lane = tid & 63;
  const int wave = tid >> 6;
  const int wm = wave >> 1, wn = wave & 1;
  const long brow = (long)blockIdx.y * 128;
  const long bcol = (long)blockIdx.x * 128;

  f32x4 acc[4][4] = {};

  for (int k0 = 0; k0 < K; k0 += 64) {
    __syncthreads();
#pragma unroll
    for (int i = 0; i < 4; ++i) {
      const int s  = i * 256 + tid;
      const int r  = s >> 3;
      const int cs = s & 7;
      const int col = ((cs ^ (r & 7)) << 3);
      *reinterpret_cast<short8*>(&As[s << 3]) =
          *reinterpret_cast<const short8*>(&A[(brow + r) * K + k0 + col]);
      *reinterpret_cast<short8*>(&Bs[s << 3]) =
          *reinterpret_cast<const short8*>(&Bt[(bcol + r) * K + k0 + col]);
    }
    __syncthreads();
#pragma unroll
    for (int kk = 0; kk < 2; ++kk) {
      short8 af[4], bq[4];
      const int cc = (kk << 2) + (lane >> 4);
#pragma unroll
      for (int m = 0; m < 4; ++m) {
        const int r = wm * 64 + m * 16 + (lane & 15);
        af[m] = *reinterpret_cast<const short8*>(&As[((r << 3) + (cc ^ (r & 7))) << 3]);
      }
#pragma unroll
      for (int n = 0; n < 4; ++n) {
        const int r = wn * 64 + n * 16 + (lane & 15);
        bq[n] = *reinterpret_cast<const short8*>(&Bs[((r << 3) + (cc ^ (r & 7))) << 3]);
      }
#pragma unroll
      for (int m = 0; m < 4; ++m)
#pragma unroll
        for (int n = 0; n < 4; ++n)
          acc[m][n] = __builtin_amdgcn_mfma_f32_16x16x32_bf16(af[m], bq[n], acc[m][n], 0, 0, 0);
    }
  }

#pragma unroll
  for (int m = 0; m < 4; ++m) {
    const long row0 = brow + wm * 64 + m * 16 + ((lane >> 4) << 2);
#pragma unroll
    for (int n = 0; n < 4; ++n) {
      const long col = bcol + wn * 64 + n * 16 + (lane & 15);
#pragma unroll
      for (int j = 0; j < 4; ++j) {
        const long idx = (row0 + j) * N + col;
        const float v = acc[m][n][j];
        if constexpr (EPI == EPI_BF16) {
          reinterpret_cast<bf16*>(Cp)[idx] = __float2bfloat16(v);
        } else if constexpr (EPI == EPI_SCALE_F32) {
          reinterpret_cast<float*>(Cp)[idx] = v * scale;
        } else if constexpr (EPI == EPI_BIAS_BF16) {
          reinterpret_cast<bf16*>(Cp)[idx] = __float2bfloat16(v + bias[col]);
        } else if constexpr (EPI == EPI_BIAS_F32) {
          reinterpret_cast<float*>(Cp)[idx] = v + bias[col];
        }
      }
    }
  }
}

// ---------------------------------------------------------------------------
__global__ __launch_bounds__(256)
void k_convert_bf16(const float* __restrict__ in, bf16* __restrict__ out, long n4)
{
  const long i = (long)blockIdx.x * 256 + threadIdx.x;
  if (i >= n4) return;
  const f32x4 v = *reinterpret_cast<const f32x4*>(&in[i * 4]);
  bf16 o[4] __attribute__((aligned(8)));
#pragma unroll
  for (int j = 0; j < 4; ++j) o[j] = __float2bfloat16(v[j]);
  *reinterpret_cast<uint2v*>(&out[i * 4]) = *reinterpret_cast<uint2v*>(o);
}

__global__ __launch_bounds__(256)
void k_convert_fp8(const float* __restrict__ in, u8* __restrict__ out, long n4)
{
  const long i = (long)blockIdx.x * 256 + threadIdx.x;
  if (i >= n4) return;
  const f32x4 v = *reinterpret_cast<const f32x4*>(&in[i * 4]);
  u8 o[4] __attribute__((aligned(4)));
#pragma unroll
  for (int j = 0; j < 4; ++j) o[j] = f32_to_fp8(v[j]);
  *reinterpret_cast<unsigned int*>(&out[i * 4]) = *reinterpret_cast<unsigned int*>(o);
}

__global__ __launch_bounds__(256)
void k_transpose_bf16(const float* __restrict__ in, bf16* __restrict__ out, int R, int C)
{
  __shared__ float t[64][65];
  const int bc = blockIdx.x << 6;
  const int br = blockIdx.y << 6;
  for (int i = threadIdx.x; i < 4096; i += 256) {
    const int r = i >> 6, c = i & 63;
    t[r][c] = in[(long)(br + r) * C + (bc + c)];
  }
  __syncthreads();
  for (int i = threadIdx.x; i < 4096; i += 256) {
    const int r = i >> 6, c = i & 63;
    out[(long)(bc + r) * R + (br + c)] = __float2bfloat16(t[c][r]);
  }
}

__global__ __launch_bounds__(256)
void k_transpose_fp8(const float* __restrict__ in, u8* __restrict__ out, int R, int C)
{
  __shared__ float t[64][65];
  const int bc = blockIdx.x << 6;
  const int br = blockIdx.y << 6;
  for (int i = threadIdx.x; i < 4096; i += 256) {
    const int r = i >> 6, c = i & 63;
    t[r][c] = in[(long)(br + r) * C + (bc + c)];
  }
  __syncthreads();
  for (int i = threadIdx.x; i < 4096; i += 256) {
    const int r = i >> 6, c = i & 63;
    out[(long)(bc + r) * R + (br + c)] = f32_to_fp8(t[c][r]);
  }
}

__global__ __launch_bounds__(256)
void k_gather_fp8(const float* __restrict__ src, const int* __restrict__ map,
                  u8* __restrict__ dst, int cols)
{
  const long i = (long)blockIdx.x * 256 + threadIdx.x;
  const int cpr = cols >> 2;
  const int row = (int)(i / cpr);
  const int c4  = (int)(i % cpr) << 2;
  const f32x4 v = *reinterpret_cast<const f32x4*>(&src[(long)map[row] * cols + c4]);
  u8 o[4] __attribute__((aligned(4)));
#pragma unroll
  for (int j = 0; j < 4; ++j) o[j] = f32_to_fp8(v[j]);
  *reinterpret_cast<unsigned int*>(&dst[(long)row * cols + c4]) =
      *reinterpret_cast<unsigned int*>(o);
}

__global__ __launch_bounds__(256)
void k_gather_rows8(const u8* __restrict__ src, const int* __restrict__ map,
                    u8* __restrict__ dst, int cols)
{
  const long i = (long)blockIdx.x * 256 + threadIdx.x;
  const int cpr = cols >> 4;
  const int row = (int)(i / cpr);
  const int c16 = (int)(i % cpr) << 4;
  *reinterpret_cast<int4v*>(&dst[(long)row * cols + c16]) =
      *reinterpret_cast<const int4v*>(&src[(long)map[row] * cols + c16]);
}

__global__ __launch_bounds__(256)
void k_softmax_topk(const float* __restrict__ scores, int* __restrict__ tki,
                    float* __restrict__ tkw)
{
  const int b = blockIdx.x;
  const float* row = scores + (long)b * Nn;
  const int tid = threadIdx.x;
  __shared__ float red[8];
  __shared__ float cv[2048];
  __shared__ int   ci[2048];

  float mx = -INFINITY;
  for (int i = tid; i < Nn; i += 256) mx = fmaxf(mx, row[i]);
#pragma unroll
  for (int o = 32; o; o >>= 1) mx = fmaxf(mx, __shfl_down(mx, o));
  if ((tid & 63) == 0) red[tid >> 6] = mx;
  __syncthreads();
  mx = fmaxf(fmaxf(red[0], red[1]), fmaxf(red[2], red[3]));

  float tv[8]; int ti[8];
#pragma unroll
  for (int j = 0; j < 8; ++j) { tv[j] = -INFINITY; ti[j] = 0x7fffffff; }
  float sum = 0.f;
  for (int i = tid; i < Nn; i += 256) {
    const float v = row[i];
    sum += expf(v - mx);
    if (v > tv[7]) {
      tv[7] = v; ti[7] = i;
#pragma unroll
      for (int j = 7; j > 0; --j) {
        const bool sw = (tv[j] > tv[j-1]) || (tv[j] == tv[j-1] && ti[j] < ti[j-1]);
        if (sw) {
          const float fv = tv[j]; tv[j] = tv[j-1]; tv[j-1] = fv;
          const int   iv = ti[j]; ti[j] = ti[j-1]; ti[j-1] = iv;
        }
      }
    }
  }
  float s2 = sum;
#pragma unroll
  for (int o = 32; o; o >>= 1) s2 += __shfl_down(s2, o);
  if ((tid & 63) == 0) red[4 + (tid >> 6)] = s2;

#pragma unroll
  for (int j = 0; j < 8; ++j) { cv[tid * 8 + j] = tv[j]; ci[tid * 8 + j] = ti[j]; }
  __syncthreads();
  const float denom = red[4] + red[5] + red[6] + red[7];

  if (tid < 64) {
    for (int p = 0; p < 8; ++p) {
      float bv = -INFINITY; int bi = 0x7fffffff;
      for (int q = 0; q < 32; ++q) {
        const int slot = tid + (q << 6);
        const float v = cv[slot]; const int id = ci[slot];
        if (v > bv || (v == bv && id < bi)) { bv = v; bi = id; }
      }
#pragma unroll
      for (int o = 32; o; o >>= 1) {
        const float ov = __shfl_xor(bv, o);
        const int   oi = __shfl_xor(bi, o);
        if (ov > bv || (ov == bv && oi < bi)) { bv = ov; bi = oi; }
      }
      if (tid == 0) { tki[b * 8 + p] = bi; tkw[b * 8 + p] = expf(bv - mx) / denom; }
      for (int q = 0; q < 32; ++q) {
        const int slot = tid + (q << 6);
        if (ci[slot] == bi) cv[slot] = -INFINITY;
      }
    }
  }
}

__global__ __launch_bounds__(256)
void k_agg_xa(const float* __restrict__ x, const bf16* __restrict__ hout,
              const float* __restrict__ tkw, bf16* __restrict__ xa)
{
  const long i = (long)blockIdx.x * 256 + threadIdx.x;
  const int b = (int)(i >> 12);
  const int d = (int)(i & 4095);
  float a = x[i];
#pragma unroll
  for (int k = 0; k < 8; ++k)
    a += tkw[b * 8 + k] * __bfloat162float(hout[(((long)b * 8 + k) << 12) + d]);
  xa[i] = __float2bfloat16(a);
}

__global__ __launch_bounds__(256)
void k_conf(const float* __restrict__ fin, const float* __restrict__ Wc,
            float* __restrict__ conf)
{
  const int b = blockIdx.x;
  float s = 0.f;
  for (int d = threadIdx.x; d < Dd; d += 256)
    s += fin[(long)b * Dd + d] * Wc[d];
#pragma unroll
  for (int o = 32; o; o >>= 1) s += __shfl_down(s, o);
  __shared__ float r4[4];
  if ((threadIdx.x & 63) == 0) r4[threadIdx.x >> 6] = s;
  __syncthreads();
  if (threadIdx.x == 0) {
    const float t = r4[0] + r4[1] + r4[2] + r4[3];
    conf[b] = 1.f / (1.f + expf(-t));
  }
}

// ---------------------------------------------------------------------------
template<int EPI>
static inline void launch_gemm(const bf16* A, const bf16* Bt, void* C,
                               const float* bias, float scale,
                               int M, int N, int K, hipStream_t st)
{
  gemm_nt<EPI><<<dim3(N / 128, M / 128), 256, 0, st>>>(A, Bt, C, bias, scale, M, N, K);
}

template<int EPI>
static inline void launch_mx(const u8* A, const u8* Bt, void* C,
                             const u8* sel, const float* bias,
                             int M, int N, int K, hipStream_t st)
{
  gemm_mx<EPI><<<dim3((M >> 7) * (N >> 7)), 256, 0, st>>>(A, Bt, C, sel, bias, 1.f, M, N, K);
}

extern "C" void kernel_launch(void* const* d_in, const int* in_sizes, int n_in,
                              void* d_out, int out_size, void* d_ws, size_t ws_size,
                              hipStream_t stream)
{
  const float* x   = (const float*)d_in[0];
  const float* ne  = (const float*)d_in[1];
  const float* adj = (const float*)d_in[2];
  const float* Wq  = (const float*)d_in[3];
  const float* Wk  = (const float*)d_in[4];
  const float* W1  = (const float*)d_in[5];
  const float* b1  = (const float*)d_in[6];
  const float* W2  = (const float*)d_in[7];
  const float* b2  = (const float*)d_in[8];
  const float* Wc  = (const float*)d_in[9];
  const float* Wo  = (const float*)d_in[10];
  const float* bo  = (const float*)d_in[11];
  float* out = (float*)d_out;

  char* ws = (char*)d_ws;
  u8*    ne8   = (u8*)(ws);                          // 32 MiB
  u8*    neT8  = (u8*)(ws + (32ll  << 20));          // 32 MiB
  u8*    adjG8 = (u8*)(ws + (64ll  << 20));          // 32 MiB -> hout (bf16) later
  bf16*  hout  = (bf16*)(ws + (64ll << 20));
  bf16*  keys  = (bf16*)(ws + (96ll  << 20));        // 64 MiB
  void*  slotW = (void*)(ws + (160ll << 20));        // 32 MiB
  u8*    sel8  = (u8*)(ws + (192ll << 20));          // 16 MiB
  u8*    msg8  = (u8*)(ws + (208ll << 20));          // 16 MiB -> hmid8 later
  u8*    hmid8 = msg8;
  float* scores= (float*)(ws + (224ll << 20));       // 16 MiB -> enh8 later
  u8*    enh8  = (u8*)(ws + (224ll << 20));
  bf16*  xbf   = (bf16*)(ws + (240ll << 20));
  bf16*  qbf   = (bf16*)(ws + (244ll << 20));
  bf16*  xa    = (bf16*)(ws + (248ll << 20));
  int*   tki   = (int*)(ws + (252ll << 20));
  float* tkw   = (float*)(ws + (252ll << 20) + 16384);

  const long neN4 = (long)Nn * Dd / 4;
  const long xN4  = (long)Bsz * Dd / 4;

  // 1. node_emb -> fp8
  k_convert_fp8<<<(int)(neN4 / 256), 256, 0, stream>>>(ne, ne8, neN4);
  // 2. Wk^T -> fp8
  k_transpose_fp8<<<dim3(64, 64), 256, 0, stream>>>(Wk, (u8*)slotW, Dd, Dd);
  // 3. keys = ne @ Wk  (MX fp8, bf16 out)
  launch_mx<EPI_BF16>(ne8, (u8*)slotW, keys, nullptr, nullptr, Nn, Dd, Dd, stream);
  // 4. x -> bf16
  k_convert_bf16<<<(int)(xN4 / 256), 256, 0, stream>>>(x, xbf, xN4);
  // 5. Wq^T (bf16)
  k_transpose_bf16<<<dim3(64, 64), 256, 0, stream>>>(Wq, (bf16*)slotW, Dd, Dd);
  // 6. q = x @ Wq
  launch_gemm<EPI_BF16>(xbf, (bf16*)slotW, qbf, nullptr, 1.f, Bsz, Dd, Dd, stream);
  // 7. scores = (q @ keys^T) / 64
  launch_gemm<EPI_SCALE_F32>(qbf, keys, scores, nullptr, 1.f / 64.f, Bsz, Nn, Dd, stream);
  // 8. softmax stats + top-8
  k_softmax_topk<<<Bsz, 256, 0, stream>>>(scores, tki, tkw);
  // 9. sel8 = ne8[topk]
  k_gather_rows8<<<(int)((long)4096 * Dd / 16 / 256), 256, 0, stream>>>(ne8, tki, sel8, Dd);
  // 10. adjG8 = fp8(adj[topk])
  k_gather_fp8<<<(int)((long)4096 * Nn / 4 / 256), 256, 0, stream>>>(adj, tki, adjG8, Nn);
  // 11. ne^T -> fp8
  k_transpose_fp8<<<dim3(Dd / 64, Nn / 64), 256, 0, stream>>>(ne, neT8, Nn, Dd);
  // 12. msg = adjG @ ne  (MX, fp8 out)
  launch_mx<EPI_FP8>(adjG8, neT8, msg8, nullptr, nullptr, 4096, Dd, Nn, stream);
  // 13. enh = sel + 0.1 * (msg @ sel^T)  (scores dead -> enh8)
  launch_mx<EPI_ENH_FP8>(msg8, sel8, enh8, sel8, nullptr, 4096, Dd, Dd, stream);
  // 14. W1^T -> fp8
  k_transpose_fp8<<<dim3(Hh / 64, Dd / 64), 256, 0, stream>>>(W1, (u8*)slotW, Dd, Hh);
  // 15. hmid = gelu(enh @ W1 + b1)  (msg dead -> hmid8)
  launch_mx<EPI_GELU_FP8>(enh8, (u8*)slotW, hmid8, nullptr, b1, 4096, Hh, Dd, stream);
  // 16. W2^T -> fp8
  k_transpose_fp8<<<dim3(Dd / 64, Hh / 64), 256, 0, stream>>>(W2, (u8*)slotW, Hh, Dd);
  // 17. hout = hmid @ W2 + b2  (adjG dead -> hout; bf16 out)
  launch_mx<EPI_BIAS_BF16>(hmid8, (u8*)slotW, hout, nullptr, b2, 4096, Dd, Hh, stream);
  // 18. xa = bf16(x + sum_k w*hout)
  k_agg_xa<<<(int)((long)Bsz * Dd / 256), 256, 0, stream>>>(x, hout, tkw, xa);
  // 19. Wo^T (bf16)
  k_transpose_bf16<<<dim3(64, 64), 256, 0, stream>>>(Wo, (bf16*)slotW, Dd, Dd);
  // 20. final = xa @ Wo + bo -> d_out (f32)
  launch_gemm<EPI_BIAS_F32>(xa, (bf16*)slotW, out, bo, 1.f, Bsz, Dd, Dd, stream);
  // 21. conf = sigmoid(final @ Wc)
  k_conf<<<Bsz, 256, 0, stream>>>(out, Wc, out + (long)Bsz * Dd);
}

// Round 11
// 939.310 us; speedup vs baseline: 1.2467x; 1.2467x over previous
//
#include <hip/hip_runtime.h>
#include <hip/hip_bf16.h>
#include <math.h>

using bf16 = __hip_bfloat16;
using u8 = unsigned char;

typedef __attribute__((ext_vector_type(8))) short short8;   // 8 bf16
typedef __attribute__((ext_vector_type(4))) float f32x4;
typedef __attribute__((ext_vector_type(16))) float f32x16;
typedef __attribute__((ext_vector_type(4))) int int4v;
typedef __attribute__((ext_vector_type(8))) int int32x8;
typedef __attribute__((ext_vector_type(2))) unsigned int uint2v;

static constexpr int Bsz = 512, Nn = 8192, Dd = 4096, Hh = 2048;

enum { EPI_BF16 = 0, EPI_SCALE_F32, EPI_BIAS_BF16, EPI_BIAS_F32,
       EPI_FP8, EPI_ENH_FP8, EPI_GELU_FP8 };

// ---------------------------------------------------------------------------
// fp8 e4m3fn encode (RNE) / decode — bit-exact, proven r7-r10
// ---------------------------------------------------------------------------
__device__ __forceinline__ u8 f32_to_fp8(float x) {
  const unsigned int u = __float_as_uint(x);
  const unsigned int s = (u >> 24) & 0x80u;
  const float ax = fminf(__uint_as_float(u & 0x7fffffffu), 448.0f);
  const unsigned int au = __float_as_uint(ax);
  unsigned int b;
  if (au >= 0x3c800000u) {
    const unsigned int r = au + 0x7ffffu + ((au >> 20) & 1u);
    b = (((r >> 23) - 120u) << 3) | ((r >> 20) & 7u);
    if (b > 0x7eu) b = 0x7eu;
  } else {
    b = (unsigned int)(int)rintf(ax * 512.0f);
  }
  return (u8)(b | s);
}

__device__ __forceinline__ float fp8_to_f32(u8 b) {
  const int e = (b >> 3) & 15, m = b & 7;
  const float v = e ? __uint_as_float((unsigned)((e + 120) << 23) | ((unsigned)m << 20))
                    : (float)m * 0.001953125f;
  return (b & 0x80) ? -v : v;
}

// ---------------------------------------------------------------------------
__device__ __forceinline__ void gload_lds16(const void* g, void* l) {
  __builtin_amdgcn_global_load_lds(
      (const __attribute__((address_space(1))) void*)g,
      (__attribute__((address_space(3))) void*)l, 16, 0, 0);
}

// stage one K-half region (NR rows x 64 B). LDS dest linear [row][slotL]
// (64-B pitch); global source slot s = slotL ^ ((row>>1)&3).
// wave handles rows wave*32..+32 (two issues of 16 rows).
__device__ __forceinline__ void stage_reg(const void* g, char* region,
                                          long grow0, long pitchB, long kbyte,
                                          int wave, int lane) {
  const int rl = lane >> 2, sl = lane & 3;
  const int s = sl ^ ((rl >> 1) & 3);
  const long r0 = (long)(wave << 5) + rl;
  const char* src0 = (const char*)g + (grow0 + r0) * pitchB + kbyte + (s << 4);
  gload_lds16(src0, region + (wave << 11));
  gload_lds16(src0 + 16 * pitchB, region + (wave << 11) + 1024);
}

#define VMCNT8 asm volatile("s_waitcnt vmcnt(8)" ::: "memory")

// epilogue value -> destination (shared by both MX kernels)
template<int EPI>
__device__ __forceinline__ void epi_store(void* Cp, const u8* sel,
                                          const float* bias, float scale,
                                          long idx, long col, float v) {
  if constexpr (EPI == EPI_BF16) {
    reinterpret_cast<bf16*>(Cp)[idx] = __float2bfloat16(v);
  } else if constexpr (EPI == EPI_SCALE_F32) {
    reinterpret_cast<float*>(Cp)[idx] = v * scale;
  } else if constexpr (EPI == EPI_FP8) {
    reinterpret_cast<u8*>(Cp)[idx] = f32_to_fp8(v);
  } else if constexpr (EPI == EPI_ENH_FP8) {
    reinterpret_cast<u8*>(Cp)[idx] = f32_to_fp8(fp8_to_f32(sel[idx]) + 0.1f * v);
  } else if constexpr (EPI == EPI_GELU_FP8) {
    const float tt = v + bias[col];
    reinterpret_cast<u8*>(Cp)[idx] =
        f32_to_fp8(0.5f * tt * (1.0f + erff(tt * 0.7071067811865475f)));
  } else if constexpr (EPI == EPI_BIAS_BF16) {
    reinterpret_cast<bf16*>(Cp)[idx] = __float2bfloat16(v + bias[col]);
  } else {
    reinterpret_cast<float*>(Cp)[idx] = v + bias[col];
  }
}

// ---------------------------------------------------------------------------
// 256x256 MX NT GEMM (r9 structure, measured 1.66 PF on keys): 8 waves (2x4),
// per-wave 128x64, LDS 128 KB = ring of 4 A + 4 B regions (16 KB each),
// depth-3 prefetch, 1 barrier/step, counted vmcnt(8).
// Used for big square GEMMs (grid >= 256 blocks). M,N %256==0, K %128==0.
// ---------------------------------------------------------------------------
#define READ_AMX4(DST, RG)                                                     \
  _Pragma("unroll") for (int mr = 0; mr < 4; ++mr) {                           \
    const int off0 = ((rowA + mr * 32) << 6) + lSw;                            \
    const int4v lo = *reinterpret_cast<const int4v*>((RG) + off0);             \
    const int4v hi = *reinterpret_cast<const int4v*>((RG) + (off0 ^ 16));      \
    DST[mr] = __builtin_shufflevector(lo, hi, 0, 1, 2, 3, 4, 5, 6, 7);         \
  }

#define READ_BMX2(DST, RG)                                                     \
  _Pragma("unroll") for (int nr = 0; nr < 2; ++nr) {                           \
    const int off0 = ((rowB + nr * 32) << 6) + lSw;                            \
    const int4v lo = *reinterpret_cast<const int4v*>((RG) + off0);             \
    const int4v hi = *reinterpret_cast<const int4v*>((RG) + (off0 ^ 16));      \
    DST[nr] = __builtin_shufflevector(lo, hi, 0, 1, 2, 3, 4, 5, 6, 7);         \
  }

template<int EPI>
__global__ __launch_bounds__(512, 1)
void gemm_mx256(const u8* __restrict__ A, const u8* __restrict__ Bt,
                void* __restrict__ Cp, const u8* __restrict__ sel,
                const float* __restrict__ bias, float scale,
                int M, int N, int K)
{
  __shared__ char lds[131072];
  const int tid  = threadIdx.x;
  const int lane = tid & 63;
  const int wave = tid >> 6;
  const int wm = wave >> 2;
  const int wn = wave & 3;

  const int nblk = (M >> 8) * (N >> 8);
  const int q8 = nblk >> 3, r8 = nblk & 7;
  const int xcd = blockIdx.x & 7, pos = blockIdx.x >> 3;
  const int wg = (xcd < r8 ? xcd * (q8 + 1) : r8 * (q8 + 1) + (xcd - r8) * q8) + pos;
  const int ntx = N >> 8;
  const long bcol = (long)(wg % ntx) << 8;
  const long brow = (long)(wg / ntx) << 8;

  const int rowA = wm * 128 + (lane & 31);
  const int rowB = wn * 64 + (lane & 31);
  const int lSw = (((lane >> 5) ^ ((lane >> 2) & 1)) << 5) | (((lane >> 1) & 1) << 4);

  char* const Ar = (char*)lds;
  char* const Br = (char*)lds + 65536;

  f32x16 acc[4][2] = {};
  const int HT = K >> 6;

#pragma unroll
  for (int h = 0; h < 3; ++h) {
    stage_reg(Bt, Br + h * 16384, bcol, K, (long)h << 6, wave, lane);
    stage_reg(A,  Ar + h * 16384, brow, K, (long)h << 6, wave, lane);
  }
  VMCNT8;
  __builtin_amdgcn_s_barrier();

  for (int h = 0; h < HT; ++h) {
    const int hn = (h + 3 < HT) ? (h + 3) : (HT - 1);
    const int rg = (h + 3) & 3;
    stage_reg(Bt, Br + rg * 16384, bcol, K, (long)hn << 6, wave, lane);
    stage_reg(A,  Ar + rg * 16384, brow, K, (long)hn << 6, wave, lane);

    int32x8 aF[4], bF[2];
    READ_AMX4(aF, Ar + (h & 3) * 16384);
    READ_BMX2(bF, Br + (h & 3) * 16384);
    __builtin_amdgcn_s_setprio(1);
#pragma unroll
    for (int mr = 0; mr < 4; ++mr)
#pragma unroll
    for (int nr = 0; nr < 2; ++nr)
      acc[mr][nr] = __builtin_amdgcn_mfma_scale_f32_32x32x64_f8f6f4(
          aF[mr], bF[nr], acc[mr][nr], 0, 0, 0, 0x7f7f7f7f, 0, 0x7f7f7f7f);
    __builtin_amdgcn_s_setprio(0);

    VMCNT8;
    __builtin_amdgcn_s_barrier();
  }

#pragma unroll
  for (int mr = 0; mr < 4; ++mr)
#pragma unroll
  for (int nr = 0; nr < 2; ++nr) {
    const long col = bcol + wn * 64 + nr * 32 + (lane & 31);
#pragma unroll
    for (int reg = 0; reg < 16; ++reg) {
      const long row = brow + wm * 128 + mr * 32 +
                       (reg & 3) + 8 * (reg >> 2) + 4 * (lane >> 5);
      epi_store<EPI>(Cp, sel, bias, scale, row * N + col, col, acc[mr][nr][reg]);
    }
  }
}

// ---------------------------------------------------------------------------
// 128x128 MX NT GEMM (r10 structure, 2 blocks/CU): 4 waves (2x2), per-wave
// 64x64, LDS 64 KB ring of 4+4 regions (8 KB), depth-3, vmcnt(8).
// Used where grid coverage matters (M=512 rows, N=2048 cols, small K).
// M,N %128==0, K %128==0.
// ---------------------------------------------------------------------------
#define READ_AMX2(DST, RG)                                                     \
  _Pragma("unroll") for (int mr = 0; mr < 2; ++mr) {                           \
    const int off0 = ((rowA + mr * 32) << 6) + lSw;                            \
    const int4v lo = *reinterpret_cast<const int4v*>((RG) + off0);             \
    const int4v hi = *reinterpret_cast<const int4v*>((RG) + (off0 ^ 16));      \
    DST[mr] = __builtin_shufflevector(lo, hi, 0, 1, 2, 3, 4, 5, 6, 7);         \
  }

template<int EPI>
__global__ __launch_bounds__(256, 2)
void gemm_mx(const u8* __restrict__ A, const u8* __restrict__ Bt,
             void* __restrict__ Cp, const u8* __restrict__ sel,
             const float* __restrict__ bias, float scale,
             int M, int N, int K)
{
  __shared__ char lds[65536];
  const int tid  = threadIdx.x;
  const int lane = tid & 63;
  const int wave = tid >> 6;
  const int wm = wave >> 1;
  const int wn = wave & 1;

  const int nblk = (M >> 7) * (N >> 7);
  const int q8 = nblk >> 3, r8 = nblk & 7;
  const int xcd = blockIdx.x & 7, pos = blockIdx.x >> 3;
  const int wg = (xcd < r8 ? xcd * (q8 + 1) : r8 * (q8 + 1) + (xcd - r8) * q8) + pos;
  const int ntx = N >> 7;
  const long bcol = (long)(wg % ntx) << 7;
  const long brow = (long)(wg / ntx) << 7;

  const int rowA = wm * 64 + (lane & 31);
  const int rowB = wn * 64 + (lane & 31);
  const int lSw = (((lane >> 5) ^ ((lane >> 2) & 1)) << 5) | (((lane >> 1) & 1) << 4);

  char* const Ar = (char*)lds;
  char* const Br = (char*)lds + 32768;

  f32x16 acc[2][2] = {};
  const int HT = K >> 6;

#pragma unroll
  for (int h = 0; h < 3; ++h) {
    stage_reg(Bt, Br + h * 8192, bcol, K, (long)h << 6, wave, lane);
    stage_reg(A,  Ar + h * 8192, brow, K, (long)h << 6, wave, lane);
  }
  VMCNT8;
  __builtin_amdgcn_s_barrier();

  for (int h = 0; h < HT; ++h) {
    const int hn = (h + 3 < HT) ? (h + 3) : (HT - 1);
    const int rg = (h + 3) & 3;
    stage_reg(Bt, Br + rg * 8192, bcol, K, (long)hn << 6, wave, lane);
    stage_reg(A,  Ar + rg * 8192, brow, K, (long)hn << 6, wave, lane);

    int32x8 aF[2], bF[2];
    READ_AMX2(aF, Ar + (h & 3) * 8192);
    READ_BMX2(bF, Br + (h & 3) * 8192);
    __builtin_amdgcn_s_setprio(1);
#pragma unroll
    for (int mr = 0; mr < 2; ++mr)
#pragma unroll
    for (int nr = 0; nr < 2; ++nr)
      acc[mr][nr] = __builtin_amdgcn_mfma_scale_f32_32x32x64_f8f6f4(
          aF[mr], bF[nr], acc[mr][nr], 0, 0, 0, 0x7f7f7f7f, 0, 0x7f7f7f7f);
    __builtin_amdgcn_s_setprio(0);

    VMCNT8;
    __builtin_amdgcn_s_barrier();
  }

#pragma unroll
  for (int mr = 0; mr < 2; ++mr)
#pragma unroll
  for (int nr = 0; nr < 2; ++nr) {
    const long col = bcol + wn * 64 + nr * 32 + (lane & 31);
#pragma unroll
    for (int reg = 0; reg < 16; ++reg) {
      const long row = brow + wm * 64 + mr * 32 +
                       (reg & 3) + 8 * (reg >> 2) + 4 * (lane >> 5);
      epi_store<EPI>(Cp, sel, bias, scale, row * N + col, col, acc[mr][nr][reg]);
    }
  }
}

// ---------------------------------------------------------------------------
// 128x128 NT GEMM bf16 (4 waves) — only for final = xa @ Wo^T (output quality)
// ---------------------------------------------------------------------------
__global__ __launch_bounds__(256)
void gemm_nt_final(const bf16* __restrict__ A, const bf16* __restrict__ Bt,
                   float* __restrict__ Cp, const float* __restrict__ bias,
                   int M, int N, int K)
{
  __shared__ bf16 As[128 * 64];
  __shared__ bf16 Bs[128 * 64];
  const int tid  = threadIdx.x;
  const int lane = tid & 63;
  const int wave = tid >> 6;
  const int wm = wave >> 1, wn = wave & 1;
  const long brow = (long)blockIdx.y * 128;
  const long bcol = (long)blockIdx.x * 128;

  f32x4 acc[4][4] = {};

  for (int k0 = 0; k0 < K; k0 += 64) {
    __syncthreads();
#pragma unroll
    for (int i = 0; i < 4; ++i) {
      const int s  = i * 256 + tid;
      const int r  = s >> 3;
      const int cs = s & 7;
      const int col = ((cs ^ (r & 7)) << 3);
      *reinterpret_cast<short8*>(&As[s << 3]) =
          *reinterpret_cast<const short8*>(&A[(brow + r) * K + k0 + col]);
      *reinterpret_cast<short8*>(&Bs[s << 3]) =
          *reinterpret_cast<const short8*>(&Bt[(bcol + r) * K + k0 + col]);
    }
    __syncthreads();
#pragma unroll
    for (int kk = 0; kk < 2; ++kk) {
      short8 af[4], bq[4];
      const int cc = (kk << 2) + (lane >> 4);
#pragma unroll
      for (int m = 0; m < 4; ++m) {
        const int r = wm * 64 + m * 16 + (lane & 15);
        af[m] = *reinterpret_cast<const short8*>(&As[((r << 3) + (cc ^ (r & 7))) << 3]);
      }
#pragma unroll
      for (int n = 0; n < 4; ++n) {
        const int r = wn * 64 + n * 16 + (lane & 15);
        bq[n] = *reinterpret_cast<const short8*>(&Bs[((r << 3) + (cc ^ (r & 7))) << 3]);
      }
#pragma unroll
      for (int m = 0; m < 4; ++m)
#pragma unroll
        for (int n = 0; n < 4; ++n)
          acc[m][n] = __builtin_amdgcn_mfma_f32_16x16x32_bf16(af[m], bq[n], acc[m][n], 0, 0, 0);
    }
  }

#pragma unroll
  for (int m = 0; m < 4; ++m) {
    const long row0 = brow + wm * 64 + m * 16 + ((lane >> 4) << 2);
#pragma unroll
    for (int n = 0; n < 4; ++n) {
      const long col = bcol + wn * 64 + n * 16 + (lane & 15);
#pragma unroll
      for (int j = 0; j < 4; ++j)
        Cp[(row0 + j) * N + col] = acc[m][n][j] + bias[col];
    }
  }
}

// ---------------------------------------------------------------------------
__global__ __launch_bounds__(256)
void k_convert_fp8(const float* __restrict__ in, u8* __restrict__ out, long n4)
{
  const long i = (long)blockIdx.x * 256 + threadIdx.x;
  if (i >= n4) return;
  const f32x4 v = *reinterpret_cast<const f32x4*>(&in[i * 4]);
  u8 o[4] __attribute__((aligned(4)));
#pragma unroll
  for (int j = 0; j < 4; ++j) o[j] = f32_to_fp8(v[j]);
  *reinterpret_cast<unsigned int*>(&out[i * 4]) = *reinterpret_cast<unsigned int*>(o);
}

__global__ __launch_bounds__(256)
void k_transpose_bf16(const float* __restrict__ in, bf16* __restrict__ out, int R, int C)
{
  __shared__ float t[64][65];
  const int bc = blockIdx.x << 6;
  const int br = blockIdx.y << 6;
  for (int i = threadIdx.x; i < 4096; i += 256) {
    const int r = i >> 6, c = i & 63;
    t[r][c] = in[(long)(br + r) * C + (bc + c)];
  }
  __syncthreads();
  for (int i = threadIdx.x; i < 4096; i += 256) {
    const int r = i >> 6, c = i & 63;
    out[(long)(bc + r) * R + (br + c)] = __float2bfloat16(t[c][r]);
  }
}

__global__ __launch_bounds__(256)
void k_transpose_fp8(const float* __restrict__ in, u8* __restrict__ out, int R, int C)
{
  __shared__ float t[64][65];
  const int bc = blockIdx.x << 6;
  const int br = blockIdx.y << 6;
  for (int i = threadIdx.x; i < 4096; i += 256) {
    const int r = i >> 6, c = i & 63;
    t[r][c] = in[(long)(br + r) * C + (bc + c)];
  }
  __syncthreads();
  for (int i = threadIdx.x; i < 4096; i += 256) {
    const int r = i >> 6, c = i & 63;
    out[(long)(bc + r) * R + (br + c)] = f32_to_fp8(t[c][r]);
  }
}

__global__ __launch_bounds__(256)
void k_gather_fp8(const float* __restrict__ src, const int* __restrict__ map,
                  u8* __restrict__ dst, int cols)
{
  const long i = (long)blockIdx.x * 256 + threadIdx.x;
  const int cpr = cols >> 2;
  const int row = (int)(i / cpr);
  const int c4  = (int)(i % cpr) << 2;
  const f32x4 v = *reinterpret_cast<const f32x4*>(&src[(long)map[row] * cols + c4]);
  u8 o[4] __attribute__((aligned(4)));
#pragma unroll
  for (int j = 0; j < 4; ++j) o[j] = f32_to_fp8(v[j]);
  *reinterpret_cast<unsigned int*>(&dst[(long)row * cols + c4]) =
      *reinterpret_cast<unsigned int*>(o);
}

__global__ __launch_bounds__(256)
void k_gather_rows8(const u8* __restrict__ src, const int* __restrict__ map,
                    u8* __restrict__ dst, int cols)
{
  const long i = (long)blockIdx.x * 256 + threadIdx.x;
  const int cpr = cols >> 4;
  const int row = (int)(i / cpr);
  const int c16 = (int)(i % cpr) << 4;
  *reinterpret_cast<int4v*>(&dst[(long)row * cols + c16]) =
      *reinterpret_cast<const int4v*>(&src[(long)map[row] * cols + c16]);
}

__global__ __launch_bounds__(256)
void k_softmax_topk(const float* __restrict__ scores, int* __restrict__ tki,
                    float* __restrict__ tkw)
{
  const int b = blockIdx.x;
  const float* row = scores + (long)b * Nn;
  const int tid = threadIdx.x;
  __shared__ float red[8];
  __shared__ float cv[2048];
  __shared__ int   ci[2048];

  float mx = -INFINITY;
  for (int i = tid; i < Nn; i += 256) mx = fmaxf(mx, row[i]);
#pragma unroll
  for (int o = 32; o; o >>= 1) mx = fmaxf(mx, __shfl_down(mx, o));
  if ((tid & 63) == 0) red[tid >> 6] = mx;
  __syncthreads();
  mx = fmaxf(fmaxf(red[0], red[1]), fmaxf(red[2], red[3]));

  float tv[8]; int ti[8];
#pragma unroll
  for (int j = 0; j < 8; ++j) { tv[j] = -INFINITY; ti[j] = 0x7fffffff; }
  float sum = 0.f;
  for (int i = tid; i < Nn; i += 256) {
    const float v = row[i];
    sum += expf(v - mx);
    if (v > tv[7]) {
      tv[7] = v; ti[7] = i;
#pragma unroll
      for (int j = 7; j > 0; --j) {
        const bool sw = (tv[j] > tv[j-1]) || (tv[j] == tv[j-1] && ti[j] < ti[j-1]);
        if (sw) {
          const float fv = tv[j]; tv[j] = tv[j-1]; tv[j-1] = fv;
          const int   iv = ti[j]; ti[j] = ti[j-1]; ti[j-1] = iv;
        }
      }
    }
  }
  float s2 = sum;
#pragma unroll
  for (int o = 32; o; o >>= 1) s2 += __shfl_down(s2, o);
  if ((tid & 63) == 0) red[4 + (tid >> 6)] = s2;

#pragma unroll
  for (int j = 0; j < 8; ++j) { cv[tid * 8 + j] = tv[j]; ci[tid * 8 + j] = ti[j]; }
  __syncthreads();
  const float denom = red[4] + red[5] + red[6] + red[7];

  if (tid < 64) {
    for (int p = 0; p < 8; ++p) {
      float bv = -INFINITY; int bi = 0x7fffffff;
      for (int q = 0; q < 32; ++q) {
        const int slot = tid + (q << 6);
        const float v = cv[slot]; const int id = ci[slot];
        if (v > bv || (v == bv && id < bi)) { bv = v; bi = id; }
      }
#pragma unroll
      for (int o = 32; o; o >>= 1) {
        const float ov = __shfl_xor(bv, o);
        const int   oi = __shfl_xor(bi, o);
        if (ov > bv || (ov == bv && oi < bi)) { bv = ov; bi = oi; }
      }
      if (tid == 0) { tki[b * 8 + p] = bi; tkw[b * 8 + p] = expf(bv - mx) / denom; }
      for (int q = 0; q < 32; ++q) {
        const int slot = tid + (q << 6);
        if (ci[slot] == bi) cv[slot] = -INFINITY;
      }
    }
  }
}

__global__ __launch_bounds__(256)
void k_agg_xa(const float* __restrict__ x, const bf16* __restrict__ hout,
              const float* __restrict__ tkw, bf16* __restrict__ xa)
{
  const long i = (long)blockIdx.x * 256 + threadIdx.x;
  const int b = (int)(i >> 12);
  const int d = (int)(i & 4095);
  float a = x[i];
#pragma unroll
  for (int k = 0; k < 8; ++k)
    a += tkw[b * 8 + k] * __bfloat162float(hout[(((long)b * 8 + k) << 12) + d]);
  xa[i] = __float2bfloat16(a);
}

__global__ __launch_bounds__(256)
void k_conf(const float* __restrict__ fin, const float* __restrict__ Wc,
            float* __restrict__ conf)
{
  const int b = blockIdx.x;
  float s = 0.f;
  for (int d = threadIdx.x; d < Dd; d += 256)
    s += fin[(long)b * Dd + d] * Wc[d];
#pragma unroll
  for (int o = 32; o; o >>= 1) s += __shfl_down(s, o);
  __shared__ float r4[4];
  if ((threadIdx.x & 63) == 0) r4[threadIdx.x >> 6] = s;
  __syncthreads();
  if (threadIdx.x == 0) {
    const float t = r4[0] + r4[1] + r4[2] + r4[3];
    conf[b] = 1.f / (1.f + expf(-t));
  }
}

// ---------------------------------------------------------------------------
template<int EPI>
static inline void launch_mx256(const u8* A, const u8* Bt, void* C,
                                const u8* sel, const float* bias,
                                int M, int N, int K, hipStream_t st)
{
  gemm_mx256<EPI><<<dim3((M >> 8) * (N >> 8)), 512, 0, st>>>(A, Bt, C, sel, bias, 1.f, M, N, K);
}

template<int EPI>
static inline void launch_mx(const u8* A, const u8* Bt, void* C,
                             const u8* sel, const float* bias, float scale,
                             int M, int N, int K, hipStream_t st)
{
  gemm_mx<EPI><<<dim3((M >> 7) * (N >> 7)), 256, 0, st>>>(A, Bt, C, sel, bias, scale, M, N, K);
}

extern "C" void kernel_launch(void* const* d_in, const int* in_sizes, int n_in,
                              void* d_out, int out_size, void* d_ws, size_t ws_size,
                              hipStream_t stream)
{
  const float* x   = (const float*)d_in[0];
  const float* ne  = (const float*)d_in[1];
  const float* adj = (const float*)d_in[2];
  const float* Wq  = (const float*)d_in[3];
  const float* Wk  = (const float*)d_in[4];
  const float* W1  = (const float*)d_in[5];
  const float* b1  = (const float*)d_in[6];
  const float* W2  = (const float*)d_in[7];
  const float* b2  = (const float*)d_in[8];
  const float* Wc  = (const float*)d_in[9];
  const float* Wo  = (const float*)d_in[10];
  const float* bo  = (const float*)d_in[11];
  float* out = (float*)d_out;

  char* ws = (char*)d_ws;
  u8*    ne8   = (u8*)(ws);                          // 32 MiB
  u8*    neT8  = (u8*)(ws + (32ll  << 20));          // 32 MiB
  u8*    adjG8 = (u8*)(ws + (64ll  << 20));          // 32 MiB -> hout (bf16)
  bf16*  hout  = (bf16*)(ws + (64ll << 20));
  void*  slotW = (void*)(ws + (96ll  << 20));        // 32 MiB (W1T8/W2T8/WoT)
  u8*    Wq8   = (u8*)(ws + (128ll << 20));          // 16 MiB
  u8*    Wk8   = (u8*)(ws + (144ll << 20));          // 16 MiB
  u8*    PT8   = (u8*)(ws + (160ll << 20));          // 16 MiB
  u8*    xP8   = (u8*)(ws + (176ll << 20));          // 2 MiB
  float* scores= (float*)(ws + (180ll << 20));       // 16 MiB
  u8*    sel8  = (u8*)(ws + (196ll << 20));          // 16 MiB
  u8*    msg8  = (u8*)(ws + (212ll << 20));          // 16 MiB -> hmid8
  u8*    hmid8 = msg8;
  u8*    enh8  = (u8*)(ws + (228ll << 20));          // 16 MiB
  u8*    x8    = (u8*)(ws + (244ll << 20));          // 2 MiB
  bf16*  xa    = (bf16*)(ws + (248ll << 20));        // 4 MiB
  int*   tki   = (int*)(ws + (252ll << 20));
  float* tkw   = (float*)(ws + (252ll << 20) + 16384);

  // 1. straight fp8 converts (no transposes needed for the scores path)
  k_convert_fp8<<<(int)((long)Nn * Dd / 4 / 256), 256, 0, stream>>>(ne, ne8, (long)Nn * Dd / 4);
  k_convert_fp8<<<(int)((long)Dd * Dd / 4 / 256), 256, 0, stream>>>(Wk, Wk8, (long)Dd * Dd / 4);
  k_convert_fp8<<<(int)((long)Dd * Dd / 4 / 256), 256, 0, stream>>>(Wq, Wq8, (long)Dd * Dd / 4);
  k_convert_fp8<<<(int)((long)Bsz * Dd / 4 / 256), 256, 0, stream>>>(x, x8, (long)Bsz * Dd / 4);

  // 2. PT = Wk @ Wq^T   (PT[e][d] = sum_k Wk[e][k] Wq[d][k]) -> fp8
  launch_mx256<EPI_FP8>(Wk8, Wq8, PT8, nullptr, nullptr, Dd, Dd, Dd, stream);
  // 3. xP = x @ PT^T  (= x @ Wq @ Wk^T) -> fp8
  launch_mx<EPI_FP8>(x8, PT8, xP8, nullptr, nullptr, 1.f, Bsz, Dd, Dd, stream);
  // 4. scores = (xP @ ne^T) / 64 -> f32
  launch_mx<EPI_SCALE_F32>(xP8, ne8, scores, nullptr, nullptr, 1.f / 64.f,
                           Bsz, Nn, Dd, stream);
  // 5. softmax stats + top-8
  k_softmax_topk<<<Bsz, 256, 0, stream>>>(scores, tki, tkw);
  // 6. sel8 = ne8[topk]
  k_gather_rows8<<<(int)((long)4096 * Dd / 16 / 256), 256, 0, stream>>>(ne8, tki, sel8, Dd);
  // 7. adjG8 = fp8(adj[topk])
  k_gather_fp8<<<(int)((long)4096 * Nn / 4 / 256), 256, 0, stream>>>(adj, tki, adjG8, Nn);
  // 8. ne^T -> fp8 (needed for msg only)
  k_transpose_fp8<<<dim3(Dd / 64, Nn / 64), 256, 0, stream>>>(ne, neT8, Nn, Dd);
  // 9. msg = adjG @ ne -> fp8
  launch_mx256<EPI_FP8>(adjG8, neT8, msg8, nullptr, nullptr, 4096, Dd, Nn, stream);
  // 10. enh = sel + 0.1 * (msg @ sel^T) -> fp8
  launch_mx256<EPI_ENH_FP8>(msg8, sel8, enh8, sel8, nullptr, 4096, Dd, Dd, stream);
  // 11. W1^T -> fp8
  k_transpose_fp8<<<dim3(Hh / 64, Dd / 64), 256, 0, stream>>>(W1, (u8*)slotW, Dd, Hh);
  // 12. hmid = gelu(enh @ W1 + b1) -> fp8 (msg dead -> hmid8)
  launch_mx<EPI_GELU_FP8>(enh8, (u8*)slotW, hmid8, nullptr, b1, 1.f, 4096, Hh, Dd, stream);
  // 13. W2^T -> fp8
  k_transpose_fp8<<<dim3(Dd / 64, Hh / 64), 256, 0, stream>>>(W2, (u8*)slotW, Hh, Dd);
  // 14. hout = hmid @ W2 + b2 -> bf16 (adjG dead -> hout)
  launch_mx<EPI_BIAS_BF16>(hmid8, (u8*)slotW, hout, nullptr, b2, 1.f, 4096, Dd, Hh, stream);
  // 15. xa = bf16(x + sum_k w*hout)
  k_agg_xa<<<(int)((long)Bsz * Dd / 256), 256, 0, stream>>>(x, hout, tkw, xa);
  // 16. Wo^T (bf16 — output quality)
  k_transpose_bf16<<<dim3(64, 64), 256, 0, stream>>>(Wo, (bf16*)slotW, Dd, Dd);
  // 17. final = xa @ Wo + bo -> d_out (f32)
  gemm_nt_final<<<dim3(Dd / 128, Bsz / 128), 256, 0, stream>>>(
      xa, (bf16*)slotW, out, bo, Bsz, Dd, Dd);
  // 18. conf = sigmoid(final @ Wc)
  k_conf<<<Bsz, 256, 0, stream>>>(out, Wc, out + (long)Bsz * Dd);
}